// Round 10
// baseline (363.711 us; speedup 1.0000x reference)
//
#include <hip/hip_runtime.h>
#include <cstdint>
#include <cstddef>

// B=2, S=1024, D=512, NH=16 (chunk width), C=32 chunks.
// weights output (C,B,S,S) fp32 = 256 MiB written once, never re-read (PV fused).
// out_pre scramble: (c,b,m,h) -> [c>>4][(c&15)*64 + (m>>4)][(m&15)*32 + b*16 + h]

// ---------------------------------------------------------------------------
// NT GEMM body: P[M][512] = X[M][512] * W[512][512]^T   (tiles 64x64x32)
// ---------------------------------------------------------------------------
__device__ __forceinline__ void gemm_nt_body(const float* __restrict__ X,
                                             const float* __restrict__ W,
                                             float* __restrict__ P)
{
    __shared__ float As[32][68];
    __shared__ float Bs[32][68];
    const int t  = threadIdx.x;
    const int tx = t & 15, ty = t >> 4;
    const int m0 = blockIdx.y << 6;
    const int n0 = blockIdx.x << 6;
    float acc[4][4] = {};
    for (int k0 = 0; k0 < 512; k0 += 32) {
#pragma unroll
        for (int rep = 0; rep < 2; ++rep) {
            int f  = rep * 256 + t;
            int r  = f >> 3, c4 = f & 7;
            float4 xv = *(const float4*)(X + (size_t)(m0 + r) * 512 + k0 + c4 * 4);
            As[c4 * 4 + 0][r] = xv.x; As[c4 * 4 + 1][r] = xv.y;
            As[c4 * 4 + 2][r] = xv.z; As[c4 * 4 + 3][r] = xv.w;
            float4 wv = *(const float4*)(W + (size_t)(n0 + r) * 512 + k0 + c4 * 4);
            Bs[c4 * 4 + 0][r] = wv.x; Bs[c4 * 4 + 1][r] = wv.y;
            Bs[c4 * 4 + 2][r] = wv.z; Bs[c4 * 4 + 3][r] = wv.w;
        }
        __syncthreads();
#pragma unroll
        for (int kk = 0; kk < 32; ++kk) {
            float4 av = *(const float4*)(&As[kk][ty * 4]);
            float4 bv = *(const float4*)(&Bs[kk][tx * 4]);
            float a[4] = {av.x, av.y, av.z, av.w};
            float b[4] = {bv.x, bv.y, bv.z, bv.w};
#pragma unroll
            for (int i = 0; i < 4; ++i)
#pragma unroll
                for (int j = 0; j < 4; ++j)
                    acc[i][j] += a[i] * b[j];
        }
        __syncthreads();
    }
#pragma unroll
    for (int i = 0; i < 4; ++i) {
        float4 o = make_float4(acc[i][0], acc[i][1], acc[i][2], acc[i][3]);
        *(float4*)(P + (size_t)(m0 + ty * 4 + i) * 512 + n0 + tx * 4) = o;
    }
}

__global__ __launch_bounds__(256, 2) void proj3_kernel(
    const float* __restrict__ Q, const float* __restrict__ K, const float* __restrict__ V,
    const float* __restrict__ Wq, const float* __restrict__ Wk, const float* __restrict__ Wv,
    float* __restrict__ q, float* __restrict__ k, float* __restrict__ v)
{
    const float* X; const float* W; float* P;
    if (blockIdx.z == 0)      { X = Q; W = Wq; P = q; }
    else if (blockIdx.z == 1) { X = K; W = Wk; P = k; }
    else                      { X = V; W = Wv; P = v; }
    gemm_nt_body(X, W, P);
}

__global__ __launch_bounds__(256, 2) void outproj_kernel(
    const float* __restrict__ att, const float* __restrict__ Wo, float* __restrict__ out)
{
    gemm_nt_body(att, Wo, out);
}

// bf16 round-to-nearest-even pack of two floats into one u32 (lo=a, hi=b)
__device__ __forceinline__ unsigned pk_bf16(float a, float b) {
    unsigned ua = __float_as_uint(a), ub = __float_as_uint(b);
    ua = (ua + 0x7fffu + ((ua >> 16) & 1u)) >> 16;
    ub = (ub + 0x7fffu + ((ub >> 16) & 1u)) >> 16;
    return ua | (ub << 16);
}
// unpack bf16 pair with scale
__device__ __forceinline__ void upk_bf16(unsigned p, float iv, float& a, float& b) {
    a = __uint_as_float(p << 16) * iv;
    b = __uint_as_float(p & 0xffff0000u) * iv;
}

// ---------------------------------------------------------------------------
// Fused scores + softmax + weights-write + PV.  v9 = v8 structure, e packed.
// Ledger (256-thread): (1,1)->alloc-as-needed(232,ok); lb(256,2)->128+spill;
// (1,2)->min(need,256), spills iff need>256. R9 needed ~265 -> spilled 4%.
// Fix: pack e as bf16 pairs (ep[4][8]=32 regs, -60 vs fp32 e[4][16]) with a
// SINGLE PV pass (no R5 H-split; ep unpacked at 2 sites, ec[4][4] live only
// per i-block). Natural peak ~130 -> alloc ~180-220 <= 256 -> no spill AND
// 2 waves/SIMD (LDS 74 KiB = 2 blocks/CU; VGPR <= 256 = 2 waves/SIMD).
//  - K,V staged as RNE bf16 pairs (conflict-free, R8/R9: 0 conflicts).
//  - q pre-scaled by 0.25 at staging.
//  - R=4 rows/pass, 8 passes/wave, 128 rows/block, 512 blocks.
//  - 6-step in-place reduce-scatter butterfly (R1/R2-verified mapping).
// Numerics: bf16 e -> absmax 1.95e-3 measured (R5/R6), threshold 6.8e-3.
// ---------------------------------------------------------------------------
__global__ __launch_bounds__(256)
__attribute__((amdgpu_waves_per_eu(1, 2)))
void attn_fused_kernel(
    const float* __restrict__ q, const float* __restrict__ k, const float* __restrict__ v,
    float* __restrict__ wts, float* __restrict__ att)
{
    __shared__ unsigned khT_p[16][514];  // [h][n-pair] bf16x2, +2 pad
    __shared__ unsigned vsT_p[16][514];
    __shared__ float qs[128][16];        // pre-scaled by 0.25
    const int t   = threadIdx.x;
    const int bid = blockIdx.x;       // 512 blocks
    const int mt  = bid & 7;          // 8 row tiles of 128
    const int cb  = bid >> 3;         // c*2 + b
    const int b   = cb & 1;
    const int c   = cb >> 1;
    const int m0  = mt << 7;

    const float* kb = k + (size_t)b * 524288 + c * 16;
    const float* vb = v + (size_t)b * 524288 + c * 16;
    const float* qb = q + (size_t)b * 524288 + (size_t)m0 * 512 + c * 16;

    // stage K,V as bf16 pairs: f enumerates (n-pair p, h-quartet hq)
#pragma unroll
    for (int rep = 0; rep < 8; ++rep) {
        int f = rep * 256 + t;        // 0..2047
        int p = f >> 2, hq = f & 3;
        float4 k0 = *(const float4*)(kb + (size_t)(2 * p)     * 512 + hq * 4);
        float4 k1 = *(const float4*)(kb + (size_t)(2 * p + 1) * 512 + hq * 4);
        khT_p[hq * 4 + 0][p] = pk_bf16(k0.x, k1.x);
        khT_p[hq * 4 + 1][p] = pk_bf16(k0.y, k1.y);
        khT_p[hq * 4 + 2][p] = pk_bf16(k0.z, k1.z);
        khT_p[hq * 4 + 3][p] = pk_bf16(k0.w, k1.w);
        float4 v0 = *(const float4*)(vb + (size_t)(2 * p)     * 512 + hq * 4);
        float4 v1 = *(const float4*)(vb + (size_t)(2 * p + 1) * 512 + hq * 4);
        vsT_p[hq * 4 + 0][p] = pk_bf16(v0.x, v1.x);
        vsT_p[hq * 4 + 1][p] = pk_bf16(v0.y, v1.y);
        vsT_p[hq * 4 + 2][p] = pk_bf16(v0.z, v1.z);
        vsT_p[hq * 4 + 3][p] = pk_bf16(v0.w, v1.w);
    }
#pragma unroll
    for (int rep = 0; rep < 2; ++rep) {
        int f = rep * 256 + t;        // 0..511
        int r = f >> 2, hq = f & 3;
        float4 qv = *(const float4*)(qb + (size_t)r * 512 + hq * 4);
        *(float4*)(&qs[r][hq * 4]) =
            make_float4(qv.x * 0.25f, qv.y * 0.25f, qv.z * 0.25f, qv.w * 0.25f);
    }
    __syncthreads();

    const int wave = t >> 6, lane = t & 63;
    float* wbase = wts + (size_t)cb * 1048576 + (size_t)m0 * 1024;

#pragma unroll 1
    for (int pq = 0; pq < 8; ++pq) {
        const int r0 = wave * 32 + pq * 4;   // row within 128-tile

        // ---- scores + exp + bf16-pack (ep[4][8] = 32 regs) ----
        unsigned ep[4][8];
        float sum[4] = {0.f, 0.f, 0.f, 0.f};
#pragma unroll
        for (int i = 0; i < 4; ++i) {
            const int pp = i * 128 + lane * 2;   // u32-pair index
            float s0[4] = {}, s1[4] = {}, s2[4] = {}, s3[4] = {};
#pragma unroll
            for (int hq = 0; hq < 4; ++hq) {
                float4 qv0 = *(const float4*)(&qs[r0 + 0][hq * 4]);
                float4 qv1 = *(const float4*)(&qs[r0 + 1][hq * 4]);
                float4 qv2 = *(const float4*)(&qs[r0 + 2][hq * 4]);
                float4 qv3 = *(const float4*)(&qs[r0 + 3][hq * 4]);
#define SC_STEP(HH, QF0, QF1, QF2, QF3)                                       \
                {                                                             \
                    uint2 u = *(const uint2*)(&khT_p[hq * 4 + HH][pp]);       \
                    float kx = __uint_as_float(u.x << 16);                    \
                    float ky = __uint_as_float(u.x & 0xffff0000u);            \
                    float kz = __uint_as_float(u.y << 16);                    \
                    float kw = __uint_as_float(u.y & 0xffff0000u);            \
                    s0[0] += QF0*kx; s0[1] += QF0*ky; s0[2] += QF0*kz; s0[3] += QF0*kw; \
                    s1[0] += QF1*kx; s1[1] += QF1*ky; s1[2] += QF1*kz; s1[3] += QF1*kw; \
                    s2[0] += QF2*kx; s2[1] += QF2*ky; s2[2] += QF2*kz; s2[3] += QF2*kw; \
                    s3[0] += QF3*kx; s3[1] += QF3*ky; s3[2] += QF3*kz; s3[3] += QF3*kw; \
                }
                SC_STEP(0, qv0.x, qv1.x, qv2.x, qv3.x)
                SC_STEP(1, qv0.y, qv1.y, qv2.y, qv3.y)
                SC_STEP(2, qv0.z, qv1.z, qv2.z, qv3.z)
                SC_STEP(3, qv0.w, qv1.w, qv2.w, qv3.w)
#undef SC_STEP
            }
#define EXP_PACK(RR, SR)                                                      \
            {                                                                 \
                float e0 = __expf(SR[0]);                                     \
                float e1 = __expf(SR[1]);                                     \
                float e2 = __expf(SR[2]);                                     \
                float e3 = __expf(SR[3]);                                     \
                sum[RR] += (e0 + e1) + (e2 + e3);                             \
                ep[RR][i*2]   = pk_bf16(e0, e1);                              \
                ep[RR][i*2+1] = pk_bf16(e2, e3);                              \
            }
            EXP_PACK(0, s0) EXP_PACK(1, s1) EXP_PACK(2, s2) EXP_PACK(3, s3)
#undef EXP_PACK
        }
        // ---- row-sum allreduce -> inv[4] ----
        float inv[4];
#pragma unroll
        for (int rr = 0; rr < 4; ++rr) {
            float s = sum[rr];
#pragma unroll
            for (int off = 32; off; off >>= 1) s += __shfl_xor(s, off);
            inv[rr] = 1.0f / s;
        }
        // ---- coalesced float4 weights store (bf16(e) * inv) ----
#pragma unroll
        for (int rr = 0; rr < 4; ++rr) {
            float* wrow = wbase + (size_t)(r0 + rr) * 1024;
#pragma unroll
            for (int i = 0; i < 4; ++i) {
                float a, bq, cq, d;
                upk_bf16(ep[rr][i*2],   inv[rr], a, bq);
                upk_bf16(ep[rr][i*2+1], inv[rr], cq, d);
                *(float4*)(&wrow[i * 256 + lane * 4]) = make_float4(a, bq, cq, d);
            }
        }
        // ---- PV partials: single pass, part[64]; ec unpacked per i-block ----
        float part[64] = {};
#pragma unroll
        for (int i = 0; i < 4; ++i) {
            const int pp = i * 128 + lane * 2;
            float ec[4][4];
#pragma unroll
            for (int rr = 0; rr < 4; ++rr) {
                upk_bf16(ep[rr][i*2],   inv[rr], ec[rr][0], ec[rr][1]);
                upk_bf16(ep[rr][i*2+1], inv[rr], ec[rr][2], ec[rr][3]);
            }
#pragma unroll
            for (int h = 0; h < 16; ++h) {
                uint2 u = *(const uint2*)(&vsT_p[h][pp]);
                float vx = __uint_as_float(u.x << 16);
                float vy = __uint_as_float(u.x & 0xffff0000u);
                float vz = __uint_as_float(u.y << 16);
                float vw = __uint_as_float(u.y & 0xffff0000u);
                part[0*16+h] += ec[0][0]*vx + ec[0][1]*vy + ec[0][2]*vz + ec[0][3]*vw;
                part[1*16+h] += ec[1][0]*vx + ec[1][1]*vy + ec[1][2]*vz + ec[1][3]*vw;
                part[2*16+h] += ec[2][0]*vx + ec[2][1]*vy + ec[2][2]*vz + ec[2][3]*vw;
                part[3*16+h] += ec[3][0]*vx + ec[3][1]*vy + ec[3][2]*vz + ec[3][3]*vw;
            }
        }
        // ---- 6-step reduce-scatter butterfly IN PLACE on part[64] ----
        // lane L ends holding the all-lane sum of original part[L], L = rr*16+h
#pragma unroll
        for (int s = 0; s < 6; ++s) {
            const int msk = 1 << s;
            const int bit = (lane >> s) & 1;
            const int cnt = 64 >> s;
#pragma unroll
            for (int u = 0; u < cnt / 2; ++u) {
                float a  = part[2 * u];
                float bb = part[2 * u + 1];
                float keep = bit ? bb : a;
                float send = bit ? a : bb;
                part[u] = keep + __shfl_xor(send, msk);
            }
        }
        // ---- scrambled att write: one float per lane ----
        const int m  = m0 + r0 + (lane >> 4);
        const int h  = lane & 15;
        const int b2 = c >> 4;
        const int m2 = (c & 15) * 64 + (m >> 4);
        const int d2 = (m & 15) * 32 + b * 16 + h;
        att[((size_t)b2 * 1024 + m2) * 512 + d2] = part[0];
    }
}

// ---------------------------------------------------------------------------
extern "C" void kernel_launch(void* const* d_in, const int* in_sizes, int n_in,
                              void* d_out, int out_size, void* d_ws, size_t ws_size,
                              hipStream_t stream)
{
    (void)in_sizes; (void)n_in; (void)out_size; (void)ws_size;
    const float* Q  = (const float*)d_in[0];
    const float* K  = (const float*)d_in[1];
    const float* V  = (const float*)d_in[2];
    const float* Wq = (const float*)d_in[3];
    const float* Wk = (const float*)d_in[4];
    const float* Wv = (const float*)d_in[5];
    const float* Wo = (const float*)d_in[6];

    float* out = (float*)d_out;
    float* wts = out + 1048576;            // weights output region (64M floats)

    float* ws  = (float*)d_ws;
    float* q   = ws;                        // 1M floats
    float* k   = ws + (1u << 20);           // 1M
    float* v   = ws + 2 * (1u << 20);       // 1M
    float* att = ws + 3 * (1u << 20);       // 1M (scrambled out_pre)

    proj3_kernel<<<dim3(8, 32, 3), 256, 0, stream>>>(Q, K, V, Wq, Wk, Wv, q, k, v);
    attn_fused_kernel<<<512, 256, 0, stream>>>(q, k, v, wts, att);
    outproj_kernel<<<dim3(8, 32, 1), 256, 0, stream>>>(att, Wo, out);
}

// Round 12
// 155.939 us; speedup vs baseline: 2.3324x; 2.3324x over previous
//
#include <hip/hip_runtime.h>
#include <cstdint>
#include <cstddef>

// B=2, S=1024, D=512, NH=16 (chunk width), C=32 chunks.
// weights (C,B,S,S) fp32 = 256 MiB written once (fused, never re-read).
// out_pre scramble: (c,b,m,h) -> [c>>4][(c&15)*64 + (m>>4)][(m&15)*32 + b*16 + h]

typedef __attribute__((ext_vector_type(8)))  short    short8;   // 8 bf16 (4 VGPR)
typedef __attribute__((ext_vector_type(4)))  float    f32x4;    // 16x16 MFMA C/D
typedef __attribute__((ext_vector_type(4)))  unsigned u32x4;

union FragU { u32x4 u; short8 s; };

// ---------------------------------------------------------------------------
// NT GEMM body: P[M][512] = X[M][512] * W[512][512]^T   (tiles 64x64x32)
// ---------------------------------------------------------------------------
__device__ __forceinline__ void gemm_nt_body(const float* __restrict__ X,
                                             const float* __restrict__ W,
                                             float* __restrict__ P)
{
    __shared__ float As[32][68];
    __shared__ float Bs[32][68];
    const int t  = threadIdx.x;
    const int tx = t & 15, ty = t >> 4;
    const int m0 = blockIdx.y << 6;
    const int n0 = blockIdx.x << 6;
    float acc[4][4] = {};
    for (int k0 = 0; k0 < 512; k0 += 32) {
#pragma unroll
        for (int rep = 0; rep < 2; ++rep) {
            int f  = rep * 256 + t;
            int r  = f >> 3, c4 = f & 7;
            float4 xv = *(const float4*)(X + (size_t)(m0 + r) * 512 + k0 + c4 * 4);
            As[c4 * 4 + 0][r] = xv.x; As[c4 * 4 + 1][r] = xv.y;
            As[c4 * 4 + 2][r] = xv.z; As[c4 * 4 + 3][r] = xv.w;
            float4 wv = *(const float4*)(W + (size_t)(n0 + r) * 512 + k0 + c4 * 4);
            Bs[c4 * 4 + 0][r] = wv.x; Bs[c4 * 4 + 1][r] = wv.y;
            Bs[c4 * 4 + 2][r] = wv.z; Bs[c4 * 4 + 3][r] = wv.w;
        }
        __syncthreads();
#pragma unroll
        for (int kk = 0; kk < 32; ++kk) {
            float4 av = *(const float4*)(&As[kk][ty * 4]);
            float4 bv = *(const float4*)(&Bs[kk][tx * 4]);
            float a[4] = {av.x, av.y, av.z, av.w};
            float b[4] = {bv.x, bv.y, bv.z, bv.w};
#pragma unroll
            for (int i = 0; i < 4; ++i)
#pragma unroll
                for (int j = 0; j < 4; ++j)
                    acc[i][j] += a[i] * b[j];
        }
        __syncthreads();
    }
#pragma unroll
    for (int i = 0; i < 4; ++i) {
        float4 o = make_float4(acc[i][0], acc[i][1], acc[i][2], acc[i][3]);
        *(float4*)(P + (size_t)(m0 + ty * 4 + i) * 512 + n0 + tx * 4) = o;
    }
}

__global__ __launch_bounds__(256, 2) void proj3_kernel(
    const float* __restrict__ Q, const float* __restrict__ K, const float* __restrict__ V,
    const float* __restrict__ Wq, const float* __restrict__ Wk, const float* __restrict__ Wv,
    float* __restrict__ q, float* __restrict__ k, float* __restrict__ v)
{
    const float* X; const float* W; float* P;
    if (blockIdx.z == 0)      { X = Q; W = Wq; P = q; }
    else if (blockIdx.z == 1) { X = K; W = Wk; P = k; }
    else                      { X = V; W = Wv; P = v; }
    gemm_nt_body(X, W, P);
}

__global__ __launch_bounds__(256, 2) void outproj_kernel(
    const float* __restrict__ att, const float* __restrict__ Wo, float* __restrict__ out)
{
    gemm_nt_body(att, Wo, out);
}

// bf16 round-to-nearest-even pack of two floats into one u32 (lo=a, hi=b)
__device__ __forceinline__ unsigned pk_bf16(float a, float b) {
    unsigned ua = __float_as_uint(a), ub = __float_as_uint(b);
    ua = (ua + 0x7fffu + ((ua >> 16) & 1u)) >> 16;
    ub = (ub + 0x7fffu + ((ub >> 16) & 1u)) >> 16;
    return ua | (ub << 16);
}

// ---------------------------------------------------------------------------
// v11: MFMA attention on the fully-verified 16x16x32 bf16 shape.
// C/D (m89/m91, HW-verified): col=lane&15, row=(lane>>4)*4+reg.
// A/B: contiguous bf16x8 per lane (row/col=lane&15, k=(lane>>4)*8+idx) — the
// m92-ladder ref-checked placement; any true-k permutation cancels because
// BOTH operands are placed with the same mapping (t_A=t_B evidenced).
// Swapped QK^T: A=K(16n x 32k: h 0..15 real, 16..31 zero via lanes g>=2),
// B=Q^T -> D=S^T: lane holds 4 n's (rows g*4+r) for col m=lane&15.
// rowsum = per-lane adds + shfl_xor(16) + shfl_xor(32). Two-pass recompute.
// PV: P round-trips through a per-wave 1KB LDS tile ([m][n-pair], written
// via verified C/D indices, read as contiguous A-frags); B=V pairs from LDS
// with the same mapping; K=32 fully used, D2 = 16m x 16h, all lanes write.
// Block = 4 waves x 16 m-rows = 64 rows; grid = 64 cb x 16 strips = 1024.
// LDS: ksF 32KB + vsT 32.9KB + pbuf 9KB = 74.9KB -> 2 blocks/CU.
// ---------------------------------------------------------------------------
__global__ __launch_bounds__(256)
__attribute__((amdgpu_waves_per_eu(1, 2)))
void attn_mfma_kernel(
    const float* __restrict__ q, const float* __restrict__ k, const float* __restrict__ v,
    float* __restrict__ wts, float* __restrict__ att)
{
    __shared__ unsigned ksF[64 * 128];    // [nt][(n&15)+16g][4] bf16-pair frags
    __shared__ unsigned vsT[16][514];     // [h][n-pair] bf16x2 (+pad, 0-conflict)
    __shared__ unsigned pbuf[4][16][36];  // per-wave P tile [m][n-pair], padded

    const int t     = threadIdx.x;
    const int bid   = blockIdx.x;         // 1024 blocks
    const int strip = bid & 15;           // 16 strips of 64 m-rows
    const int cb    = bid >> 4;           // c*2 + b
    const int b     = cb & 1;
    const int c     = cb >> 1;
    const int m0b   = strip << 6;

    const float* kb = k + (size_t)b * 524288 + c * 16;
    const float* vb = v + (size_t)b * 524288 + c * 16;

    // ---- stage K as A-fragments: tasks (n 0..1023, g 0..1) ----
#pragma unroll
    for (int rep = 0; rep < 8; ++rep) {
        int f = rep * 256 + t;            // 0..2047
        int n = f >> 1, gg = f & 1;
        const float* kr = kb + (size_t)n * 512 + gg * 8;
        float4 a  = *(const float4*)kr;
        float4 bq = *(const float4*)(kr + 4);
        unsigned* dst = &ksF[(n >> 4) * 128 + ((n & 15) + (gg << 4)) * 4];
        dst[0] = pk_bf16(a.x, a.y);
        dst[1] = pk_bf16(a.z, a.w);
        dst[2] = pk_bf16(bq.x, bq.y);
        dst[3] = pk_bf16(bq.z, bq.w);
    }
    // ---- stage V as [h][n-pair] bf16 pairs ----
#pragma unroll
    for (int rep = 0; rep < 8; ++rep) {
        int f = rep * 256 + t;            // p(0..511) x hq(0..3)
        int p = f >> 2, hq = f & 3;
        float4 v0 = *(const float4*)(vb + (size_t)(2 * p)     * 512 + hq * 4);
        float4 v1 = *(const float4*)(vb + (size_t)(2 * p + 1) * 512 + hq * 4);
        vsT[hq * 4 + 0][p] = pk_bf16(v0.x, v1.x);
        vsT[hq * 4 + 1][p] = pk_bf16(v0.y, v1.y);
        vsT[hq * 4 + 2][p] = pk_bf16(v0.z, v1.z);
        vsT[hq * 4 + 3][p] = pk_bf16(v0.w, v1.w);
    }
    __syncthreads();

    const int wave = t >> 6, lane = t & 63;
    const int ml = lane & 15;             // m-offset (QK^T D col) / h (PV D col)
    const int g  = lane >> 4;             // k-group
    const int m0w = m0b + wave * 16;

    // ---- Q fragment (B operand), 0.25 scale folded; k 16..31 zero ----
    FragU qf;
    if (g < 2) {
        const float* qr = q + (size_t)b * 524288
                            + (size_t)(m0w + ml) * 512 + c * 16 + g * 8;
        float4 a  = *(const float4*)qr;
        float4 bq = *(const float4*)(qr + 4);
        qf.u[0] = pk_bf16(a.x * 0.25f, a.y * 0.25f);
        qf.u[1] = pk_bf16(a.z * 0.25f, a.w * 0.25f);
        qf.u[2] = pk_bf16(bq.x * 0.25f, bq.y * 0.25f);
        qf.u[3] = pk_bf16(bq.z * 0.25f, bq.w * 0.25f);
    } else {
        qf.u = (u32x4){0, 0, 0, 0};
    }

    const f32x4 zero4 = {0.f, 0.f, 0.f, 0.f};

    // ---- pass 1: row sums ----
    float rs = 0.f;
#pragma unroll 1
    for (int nt = 0; nt < 64; ++nt) {
        FragU ka;
        if (lane < 32) ka.u = *(const u32x4*)&ksF[nt * 128 + lane * 4];
        else           ka.u = (u32x4){0, 0, 0, 0};
        f32x4 st = __builtin_amdgcn_mfma_f32_16x16x32_bf16(ka.s, qf.s, zero4, 0, 0, 0);
        rs += (__expf(st[0]) + __expf(st[1])) + (__expf(st[2]) + __expf(st[3]));
    }
    rs += __shfl_xor(rs, 16);
    rs += __shfl_xor(rs, 32);
    const float inv = 1.0f / rs;

    // ---- pass 2: weights store + PV ----
    f32x4 acc = zero4;
    float* wrow = wts + (size_t)cb * 1048576 + (size_t)(m0w + ml) * 1024;
#pragma unroll 1
    for (int ntp = 0; ntp < 32; ++ntp) {
#pragma unroll
        for (int sub = 0; sub < 2; ++sub) {
            const int nt = ntp * 2 + sub;
            FragU ka;
            if (lane < 32) ka.u = *(const u32x4*)&ksF[nt * 128 + lane * 4];
            else           ka.u = (u32x4){0, 0, 0, 0};
            f32x4 st = __builtin_amdgcn_mfma_f32_16x16x32_bf16(ka.s, qf.s, zero4, 0, 0, 0);
            float w0 = __expf(st[0]) * inv;
            float w1 = __expf(st[1]) * inv;
            float w2 = __expf(st[2]) * inv;
            float w3 = __expf(st[3]) * inv;
            // weights: reg r -> n = nt*16 + g*4 + r, row m = m0w+ml
            *(float4*)(wrow + nt * 16 + g * 4) = make_float4(w0, w1, w2, w3);
            // P tile to per-wave LDS: [m=ml][n-pair = sub*8 + g*2 + {0,1}]
            unsigned* pb = &pbuf[wave][ml][sub * 8 + g * 2];
            pb[0] = pk_bf16(w0, w1);
            pb[1] = pk_bf16(w2, w3);
        }
        // PV over this 32-n block (same-wave LDS: in-order, compiler waits)
        FragU pa, vf;
        pa.u = *(const u32x4*)&pbuf[wave][ml][g * 4];           // row m=ml, k pairs
        vf.u = *(const u32x4*)&vsT[ml][ntp * 16 + g * 4];       // col h=ml, k pairs
        acc = __builtin_amdgcn_mfma_f32_16x16x32_bf16(pa.s, vf.s, acc, 0, 0, 0);
    }

    // ---- att write (scrambled): D2 row = m-offset g*4+r, col = h = ml ----
    const int b2 = c >> 4;
#pragma unroll
    for (int r = 0; r < 4; ++r) {
        const int m  = m0w + g * 4 + r;
        const int m2 = (c & 15) * 64 + (m >> 4);
        const int d2 = (m & 15) * 32 + b * 16 + ml;
        att[((size_t)b2 * 1024 + m2) * 512 + d2] = acc[r];
    }
}

// ---------------------------------------------------------------------------
extern "C" void kernel_launch(void* const* d_in, const int* in_sizes, int n_in,
                              void* d_out, int out_size, void* d_ws, size_t ws_size,
                              hipStream_t stream)
{
    (void)in_sizes; (void)n_in; (void)out_size; (void)ws_size;
    const float* Q  = (const float*)d_in[0];
    const float* K  = (const float*)d_in[1];
    const float* V  = (const float*)d_in[2];
    const float* Wq = (const float*)d_in[3];
    const float* Wk = (const float*)d_in[4];
    const float* Wv = (const float*)d_in[5];
    const float* Wo = (const float*)d_in[6];

    float* out = (float*)d_out;
    float* wts = out + 1048576;            // weights output region (64M floats)

    float* ws  = (float*)d_ws;
    float* q   = ws;                        // 1M floats
    float* k   = ws + (1u << 20);           // 1M
    float* v   = ws + 2 * (1u << 20);       // 1M
    float* att = ws + 3 * (1u << 20);       // 1M (scrambled out_pre)

    proj3_kernel<<<dim3(8, 32, 3), 256, 0, stream>>>(Q, K, V, Wq, Wk, Wv, q, k, v);
    attn_mfma_kernel<<<1024, 256, 0, stream>>>(q, k, v, wts, att);
    outproj_kernel<<<dim3(8, 32, 1), 256, 0, stream>>>(att, Wo, out);
}

// Round 13
// 107.191 us; speedup vs baseline: 3.3931x; 1.4548x over previous
//
#include <hip/hip_runtime.h>
#include <cstdint>
#include <cstddef>

// B=2, S=1024, D=512, NH=16 (chunk width), C=32 chunks.
// weights (C,B,S,S) fp32 = 256 MiB written once (fused, never re-read).
// out_pre scramble: (c,b,m,h) -> [c>>4][(c&15)*64 + (m>>4)][(m&15)*32 + b*16 + h]

typedef __attribute__((ext_vector_type(8)))  short    short8;   // 8 bf16 (4 VGPR)
typedef __attribute__((ext_vector_type(4)))  float    f32x4;    // 16x16 MFMA C/D
typedef __attribute__((ext_vector_type(4)))  unsigned u32x4;

union FragU { u32x4 u; short8 s; };

// bf16 round-to-nearest-even pack of two floats into one u32 (lo=a, hi=b)
__device__ __forceinline__ unsigned pk_bf16(float a, float b) {
    unsigned ua = __float_as_uint(a), ub = __float_as_uint(b);
    ua = (ua + 0x7fffu + ((ua >> 16) & 1u)) >> 16;
    ub = (ub + 0x7fffu + ((ub >> 16) & 1u)) >> 16;
    return ua | (ub << 16);
}

// ---------------------------------------------------------------------------
// MFMA NT GEMM: P[M][512] = bf16(X[M][512]) * bf16(W[512][512])^T
// Same verified fragment discipline as the R12 attention kernel:
//   A row=lane&15, k=(lane>>4)*8+idx (contiguous bf16x8); B identical; D
//   col=lane&15, row=(lane>>4)*4+reg (m89/m91). t_A=t_B -> k-perm cancels.
// Block: 64m x 64n tile, 4 waves (wave = 16-row strip, 4 n-frags, 4 acc).
// K staged in two 256-halves as bf16 pairs: Xs/Ws[row][kf pad 33][4 u32],
// 66 KB -> 2 blocks/CU. Staging: kf-fastest tasks -> global reads 1KB/row
// coalesced, LDS writes lane-contiguous; compute reads ~2-way (free, m136).
// ---------------------------------------------------------------------------
__device__ __forceinline__ void gemm_nt_mfma_body(const float* __restrict__ X,
                                                  const float* __restrict__ W,
                                                  float* __restrict__ P)
{
    __shared__ unsigned Xs[64 * 33 * 4];   // 33 KB
    __shared__ unsigned Ws[64 * 33 * 4];   // 33 KB
    const int t  = threadIdx.x;
    const int m0 = blockIdx.y << 6;
    const int n0 = blockIdx.x << 6;
    const int wave = t >> 6, lane = t & 63;
    const int ml = lane & 15;              // A row / B col within 16
    const int g  = lane >> 4;              // k-group (0..3)

    f32x4 acc[4] = {{0,0,0,0}, {0,0,0,0}, {0,0,0,0}, {0,0,0,0}};

#pragma unroll 1
    for (int kh = 0; kh < 2; ++kh) {
        if (kh) __syncthreads();           // compute of prev half done
        // ---- stage X,W half: tasks f=(r 0..63, kf 0..31), kf fastest ----
#pragma unroll
        for (int rep = 0; rep < 8; ++rep) {
            int f  = rep * 256 + t;
            int kf = f & 31, r = f >> 5;
            const float* xr = X + (size_t)(m0 + r) * 512 + kh * 256 + kf * 8;
            float4 a = *(const float4*)xr;
            float4 b = *(const float4*)(xr + 4);
            unsigned* dx = &Xs[(r * 33 + kf) * 4];
            dx[0] = pk_bf16(a.x, a.y); dx[1] = pk_bf16(a.z, a.w);
            dx[2] = pk_bf16(b.x, b.y); dx[3] = pk_bf16(b.z, b.w);
            const float* wr = W + (size_t)(n0 + r) * 512 + kh * 256 + kf * 8;
            float4 c = *(const float4*)wr;
            float4 d = *(const float4*)(wr + 4);
            unsigned* dw = &Ws[(r * 33 + kf) * 4];
            dw[0] = pk_bf16(c.x, c.y); dw[1] = pk_bf16(c.z, c.w);
            dw[2] = pk_bf16(d.x, d.y); dw[3] = pk_bf16(d.z, d.w);
        }
        __syncthreads();
        // ---- compute 8 k-steps of 32 ----
#pragma unroll
        for (int ks = 0; ks < 8; ++ks) {
            const int kf = ks * 4 + g;
            FragU a;
            a.u = *(const u32x4*)&Xs[((wave * 16 + ml) * 33 + kf) * 4];
#pragma unroll
            for (int nf = 0; nf < 4; ++nf) {
                FragU bw;
                bw.u = *(const u32x4*)&Ws[((nf * 16 + ml) * 33 + kf) * 4];
                acc[nf] = __builtin_amdgcn_mfma_f32_16x16x32_bf16(
                    a.s, bw.s, acc[nf], 0, 0, 0);
            }
        }
    }
    // ---- store: D row = g*4+r (m within strip), col = ml (n within frag) ----
#pragma unroll
    for (int nf = 0; nf < 4; ++nf) {
#pragma unroll
        for (int r = 0; r < 4; ++r) {
            const int m = m0 + wave * 16 + g * 4 + r;
            P[(size_t)m * 512 + n0 + nf * 16 + ml] = acc[nf][r];
        }
    }
}

__global__ __launch_bounds__(256, 2) void proj3_kernel(
    const float* __restrict__ Q, const float* __restrict__ K, const float* __restrict__ V,
    const float* __restrict__ Wq, const float* __restrict__ Wk, const float* __restrict__ Wv,
    float* __restrict__ q, float* __restrict__ k, float* __restrict__ v)
{
    const float* X; const float* W; float* P;
    if (blockIdx.z == 0)      { X = Q; W = Wq; P = q; }
    else if (blockIdx.z == 1) { X = K; W = Wk; P = k; }
    else                      { X = V; W = Wv; P = v; }
    gemm_nt_mfma_body(X, W, P);
}

__global__ __launch_bounds__(256, 2) void outproj_kernel(
    const float* __restrict__ att, const float* __restrict__ Wo, float* __restrict__ out)
{
    gemm_nt_mfma_body(att, Wo, out);
}

// ---------------------------------------------------------------------------
// v11 MFMA attention (R12: PASSED, 1.95e-3) — unchanged.
// ---------------------------------------------------------------------------
__global__ __launch_bounds__(256)
__attribute__((amdgpu_waves_per_eu(1, 2)))
void attn_mfma_kernel(
    const float* __restrict__ q, const float* __restrict__ k, const float* __restrict__ v,
    float* __restrict__ wts, float* __restrict__ att)
{
    __shared__ unsigned ksF[64 * 128];    // [nt][(n&15)+16g][4] bf16-pair frags
    __shared__ unsigned vsT[16][514];     // [h][n-pair] bf16x2 (+pad, 0-conflict)
    __shared__ unsigned pbuf[4][16][36];  // per-wave P tile [m][n-pair], padded

    const int t     = threadIdx.x;
    const int bid   = blockIdx.x;         // 1024 blocks
    const int strip = bid & 15;           // 16 strips of 64 m-rows
    const int cb    = bid >> 4;           // c*2 + b
    const int b     = cb & 1;
    const int c     = cb >> 1;
    const int m0b   = strip << 6;

    const float* kb = k + (size_t)b * 524288 + c * 16;
    const float* vb = v + (size_t)b * 524288 + c * 16;

    // ---- stage K as A-fragments: tasks (n 0..1023, g 0..1) ----
#pragma unroll
    for (int rep = 0; rep < 8; ++rep) {
        int f = rep * 256 + t;            // 0..2047
        int n = f >> 1, gg = f & 1;
        const float* kr = kb + (size_t)n * 512 + gg * 8;
        float4 a  = *(const float4*)kr;
        float4 bq = *(const float4*)(kr + 4);
        unsigned* dst = &ksF[(n >> 4) * 128 + ((n & 15) + (gg << 4)) * 4];
        dst[0] = pk_bf16(a.x, a.y);
        dst[1] = pk_bf16(a.z, a.w);
        dst[2] = pk_bf16(bq.x, bq.y);
        dst[3] = pk_bf16(bq.z, bq.w);
    }
    // ---- stage V as [h][n-pair] bf16 pairs ----
#pragma unroll
    for (int rep = 0; rep < 8; ++rep) {
        int f = rep * 256 + t;            // p(0..511) x hq(0..3)
        int p = f >> 2, hq = f & 3;
        float4 v0 = *(const float4*)(vb + (size_t)(2 * p)     * 512 + hq * 4);
        float4 v1 = *(const float4*)(vb + (size_t)(2 * p + 1) * 512 + hq * 4);
        vsT[hq * 4 + 0][p] = pk_bf16(v0.x, v1.x);
        vsT[hq * 4 + 1][p] = pk_bf16(v0.y, v1.y);
        vsT[hq * 4 + 2][p] = pk_bf16(v0.z, v1.z);
        vsT[hq * 4 + 3][p] = pk_bf16(v0.w, v1.w);
    }
    __syncthreads();

    const int wave = t >> 6, lane = t & 63;
    const int ml = lane & 15;             // m-offset (QK^T D col) / h (PV D col)
    const int g  = lane >> 4;             // k-group
    const int m0w = m0b + wave * 16;

    // ---- Q fragment (B operand), 0.25 scale folded; k 16..31 zero ----
    FragU qf;
    if (g < 2) {
        const float* qr = q + (size_t)b * 524288
                            + (size_t)(m0w + ml) * 512 + c * 16 + g * 8;
        float4 a  = *(const float4*)qr;
        float4 bq = *(const float4*)(qr + 4);
        qf.u[0] = pk_bf16(a.x * 0.25f, a.y * 0.25f);
        qf.u[1] = pk_bf16(a.z * 0.25f, a.w * 0.25f);
        qf.u[2] = pk_bf16(bq.x * 0.25f, bq.y * 0.25f);
        qf.u[3] = pk_bf16(bq.z * 0.25f, bq.w * 0.25f);
    } else {
        qf.u = (u32x4){0, 0, 0, 0};
    }

    const f32x4 zero4 = {0.f, 0.f, 0.f, 0.f};

    // ---- pass 1: row sums ----
    float rs = 0.f;
#pragma unroll 1
    for (int nt = 0; nt < 64; ++nt) {
        FragU ka;
        if (lane < 32) ka.u = *(const u32x4*)&ksF[nt * 128 + lane * 4];
        else           ka.u = (u32x4){0, 0, 0, 0};
        f32x4 st = __builtin_amdgcn_mfma_f32_16x16x32_bf16(ka.s, qf.s, zero4, 0, 0, 0);
        rs += (__expf(st[0]) + __expf(st[1])) + (__expf(st[2]) + __expf(st[3]));
    }
    rs += __shfl_xor(rs, 16);
    rs += __shfl_xor(rs, 32);
    const float inv = 1.0f / rs;

    // ---- pass 2: weights store + PV ----
    f32x4 acc = zero4;
    float* wrow = wts + (size_t)cb * 1048576 + (size_t)(m0w + ml) * 1024;
#pragma unroll 1
    for (int ntp = 0; ntp < 32; ++ntp) {
#pragma unroll
        for (int sub = 0; sub < 2; ++sub) {
            const int nt = ntp * 2 + sub;
            FragU ka;
            if (lane < 32) ka.u = *(const u32x4*)&ksF[nt * 128 + lane * 4];
            else           ka.u = (u32x4){0, 0, 0, 0};
            f32x4 st = __builtin_amdgcn_mfma_f32_16x16x32_bf16(ka.s, qf.s, zero4, 0, 0, 0);
            float w0 = __expf(st[0]) * inv;
            float w1 = __expf(st[1]) * inv;
            float w2 = __expf(st[2]) * inv;
            float w3 = __expf(st[3]) * inv;
            // weights: reg r -> n = nt*16 + g*4 + r, row m = m0w+ml
            *(float4*)(wrow + nt * 16 + g * 4) = make_float4(w0, w1, w2, w3);
            // P tile to per-wave LDS: [m=ml][n-pair = sub*8 + g*2 + {0,1}]
            unsigned* pb = &pbuf[wave][ml][sub * 8 + g * 2];
            pb[0] = pk_bf16(w0, w1);
            pb[1] = pk_bf16(w2, w3);
        }
        // PV over this 32-n block (same-wave LDS: in-order, compiler waits)
        FragU pa, vf;
        pa.u = *(const u32x4*)&pbuf[wave][ml][g * 4];           // row m=ml, k pairs
        vf.u = *(const u32x4*)&vsT[ml][ntp * 16 + g * 4];       // col h=ml, k pairs
        acc = __builtin_amdgcn_mfma_f32_16x16x32_bf16(pa.s, vf.s, acc, 0, 0, 0);
    }

    // ---- att write (scrambled): D2 row = m-offset g*4+r, col = h = ml ----
    const int b2 = c >> 4;
#pragma unroll
    for (int r = 0; r < 4; ++r) {
        const int m  = m0w + g * 4 + r;
        const int m2 = (c & 15) * 64 + (m >> 4);
        const int d2 = (m & 15) * 32 + b * 16 + ml;
        att[((size_t)b2 * 1024 + m2) * 512 + d2] = acc[r];
    }
}

// ---------------------------------------------------------------------------
extern "C" void kernel_launch(void* const* d_in, const int* in_sizes, int n_in,
                              void* d_out, int out_size, void* d_ws, size_t ws_size,
                              hipStream_t stream)
{
    (void)in_sizes; (void)n_in; (void)out_size; (void)ws_size;
    const float* Q  = (const float*)d_in[0];
    const float* K  = (const float*)d_in[1];
    const float* V  = (const float*)d_in[2];
    const float* Wq = (const float*)d_in[3];
    const float* Wk = (const float*)d_in[4];
    const float* Wv = (const float*)d_in[5];
    const float* Wo = (const float*)d_in[6];

    float* out = (float*)d_out;
    float* wts = out + 1048576;            // weights output region (64M floats)

    float* ws  = (float*)d_ws;
    float* q   = ws;                        // 1M floats
    float* k   = ws + (1u << 20);           // 1M
    float* v   = ws + 2 * (1u << 20);       // 1M
    float* att = ws + 3 * (1u << 20);       // 1M (scrambled out_pre)

    proj3_kernel<<<dim3(8, 32, 3), 256, 0, stream>>>(Q, K, V, Wq, Wk, Wv, q, k, v);
    attn_mfma_kernel<<<1024, 256, 0, stream>>>(q, k, v, wts, att);
    outproj_kernel<<<dim3(8, 32, 1), 256, 0, stream>>>(att, Wo, out);
}

// Round 14
// 105.251 us; speedup vs baseline: 3.4557x; 1.0184x over previous
//
#include <hip/hip_runtime.h>
#include <cstdint>
#include <cstddef>

// B=2, S=1024, D=512, NH=16 (chunk width), C=32 chunks.
// weights (C,B,S,S) fp32 = 256 MiB written once (fused, never re-read).
// out_pre scramble: (c,b,m,h) -> [c>>4][(c&15)*64 + (m>>4)][(m&15)*32 + b*16 + h]

typedef __attribute__((ext_vector_type(8)))  short    short8;   // 8 bf16 (4 VGPR)
typedef __attribute__((ext_vector_type(4)))  float    f32x4;    // 16x16 MFMA C/D
typedef __attribute__((ext_vector_type(4)))  unsigned u32x4;

union FragU { u32x4 u; short8 s; };

// bf16 round-to-nearest-even pack of two floats into one u32 (lo=a, hi=b)
__device__ __forceinline__ unsigned pk_bf16(float a, float b) {
    unsigned ua = __float_as_uint(a), ub = __float_as_uint(b);
    ua = (ua + 0x7fffu + ((ua >> 16) & 1u)) >> 16;
    ub = (ub + 0x7fffu + ((ub >> 16) & 1u)) >> 16;
    return ua | (ub << 16);
}

// ---------------------------------------------------------------------------
// MFMA NT GEMM: P[M][512] = bf16(X[M][512]) * bf16(W[512][512])^T
// (R13: PASSED as part of 107us pipeline.) Verified fragment discipline:
// A row=lane&15, k=(lane>>4)*8+idx; B identical; D col=lane&15,
// row=(lane>>4)*4+reg. 64x64 tile, 2 k-halves staged as bf16 pairs.
// ---------------------------------------------------------------------------
__device__ __forceinline__ void gemm_nt_mfma_body(const float* __restrict__ X,
                                                  const float* __restrict__ W,
                                                  float* __restrict__ P)
{
    __shared__ unsigned Xs[64 * 33 * 4];   // 33 KB
    __shared__ unsigned Ws[64 * 33 * 4];   // 33 KB
    const int t  = threadIdx.x;
    const int m0 = blockIdx.y << 6;
    const int n0 = blockIdx.x << 6;
    const int wave = t >> 6, lane = t & 63;
    const int ml = lane & 15;              // A row / B col within 16
    const int g  = lane >> 4;              // k-group (0..3)

    f32x4 acc[4] = {{0,0,0,0}, {0,0,0,0}, {0,0,0,0}, {0,0,0,0}};

#pragma unroll 1
    for (int kh = 0; kh < 2; ++kh) {
        if (kh) __syncthreads();           // compute of prev half done
        // ---- stage X,W half: tasks f=(r 0..63, kf 0..31), kf fastest ----
#pragma unroll
        for (int rep = 0; rep < 8; ++rep) {
            int f  = rep * 256 + t;
            int kf = f & 31, r = f >> 5;
            const float* xr = X + (size_t)(m0 + r) * 512 + kh * 256 + kf * 8;
            float4 a = *(const float4*)xr;
            float4 b = *(const float4*)(xr + 4);
            unsigned* dx = &Xs[(r * 33 + kf) * 4];
            dx[0] = pk_bf16(a.x, a.y); dx[1] = pk_bf16(a.z, a.w);
            dx[2] = pk_bf16(b.x, b.y); dx[3] = pk_bf16(b.z, b.w);
            const float* wr = W + (size_t)(n0 + r) * 512 + kh * 256 + kf * 8;
            float4 c = *(const float4*)wr;
            float4 d = *(const float4*)(wr + 4);
            unsigned* dw = &Ws[(r * 33 + kf) * 4];
            dw[0] = pk_bf16(c.x, c.y); dw[1] = pk_bf16(c.z, c.w);
            dw[2] = pk_bf16(d.x, d.y); dw[3] = pk_bf16(d.z, d.w);
        }
        __syncthreads();
        // ---- compute 8 k-steps of 32 ----
#pragma unroll
        for (int ks = 0; ks < 8; ++ks) {
            const int kf = ks * 4 + g;
            FragU a;
            a.u = *(const u32x4*)&Xs[((wave * 16 + ml) * 33 + kf) * 4];
#pragma unroll
            for (int nf = 0; nf < 4; ++nf) {
                FragU bw;
                bw.u = *(const u32x4*)&Ws[((nf * 16 + ml) * 33 + kf) * 4];
                acc[nf] = __builtin_amdgcn_mfma_f32_16x16x32_bf16(
                    a.s, bw.s, acc[nf], 0, 0, 0);
            }
        }
    }
    // ---- store: D row = g*4+r (m within strip), col = ml (n within frag) ----
#pragma unroll
    for (int nf = 0; nf < 4; ++nf) {
#pragma unroll
        for (int r = 0; r < 4; ++r) {
            const int m = m0 + wave * 16 + g * 4 + r;
            P[(size_t)m * 512 + n0 + nf * 16 + ml] = acc[nf][r];
        }
    }
}

__global__ __launch_bounds__(256, 2) void proj3_kernel(
    const float* __restrict__ Q, const float* __restrict__ K, const float* __restrict__ V,
    const float* __restrict__ Wq, const float* __restrict__ Wk, const float* __restrict__ Wv,
    float* __restrict__ q, float* __restrict__ k, float* __restrict__ v)
{
    const float* X; const float* W; float* P;
    if (blockIdx.z == 0)      { X = Q; W = Wq; P = q; }
    else if (blockIdx.z == 1) { X = K; W = Wk; P = k; }
    else                      { X = V; W = Wv; P = v; }
    gemm_nt_mfma_body(X, W, P);
}

__global__ __launch_bounds__(256, 2) void outproj_kernel(
    const float* __restrict__ att, const float* __restrict__ Wo, float* __restrict__ out)
{
    gemm_nt_mfma_body(att, Wo, out);
}

// ---------------------------------------------------------------------------
// v12 MFMA attention: R12 structure (PASSED) widened to 8 waves/block.
// 512 threads, 128 rows/block, 512 blocks. LDS = ksF 32KB + vsT 32.9KB +
// pbuf[8][16][18] 9KB = 73.1 KiB -> 2 blocks/CU -> 16 waves/CU = 4/SIMD
// (R7/R13 structure only reached 2/SIMD; this doubles latency hiding).
// 512-thread blocks cap VGPR at 128 (ledger R2-R6); this kernel's natural
// need is ~60-100 -> predicted no spill (watch FETCH; balloon = revert).
// All fragment mappings identical to the R12-verified kernel.
// ---------------------------------------------------------------------------
__global__ __launch_bounds__(512)
void attn_mfma_kernel(
    const float* __restrict__ q, const float* __restrict__ k, const float* __restrict__ v,
    float* __restrict__ wts, float* __restrict__ att)
{
    __shared__ unsigned ksF[64 * 128];    // [nt][(n&15)+16g][4] bf16-pair frags
    __shared__ unsigned vsT[16][514];     // [h][n-pair] bf16x2 (+pad, 0-conflict)
    __shared__ unsigned pbuf[8][16][18];  // per-wave P tile [m][n-pair], padded

    const int t     = threadIdx.x;
    const int bid   = blockIdx.x;         // 512 blocks
    const int strip = bid & 7;            // 8 strips of 128 m-rows
    const int cb    = bid >> 3;           // c*2 + b
    const int b     = cb & 1;
    const int c     = cb >> 1;
    const int m0b   = strip << 7;

    const float* kb = k + (size_t)b * 524288 + c * 16;
    const float* vb = v + (size_t)b * 524288 + c * 16;

    // ---- stage K as A-fragments: tasks (n 0..1023, g 0..1) ----
#pragma unroll
    for (int rep = 0; rep < 4; ++rep) {
        int f = rep * 512 + t;            // 0..2047
        int n = f >> 1, gg = f & 1;
        const float* kr = kb + (size_t)n * 512 + gg * 8;
        float4 a  = *(const float4*)kr;
        float4 bq = *(const float4*)(kr + 4);
        unsigned* dst = &ksF[(n >> 4) * 128 + ((n & 15) + (gg << 4)) * 4];
        dst[0] = pk_bf16(a.x, a.y);
        dst[1] = pk_bf16(a.z, a.w);
        dst[2] = pk_bf16(bq.x, bq.y);
        dst[3] = pk_bf16(bq.z, bq.w);
    }
    // ---- stage V as [h][n-pair] bf16 pairs ----
#pragma unroll
    for (int rep = 0; rep < 4; ++rep) {
        int f = rep * 512 + t;            // p(0..511) x hq(0..3)
        int p = f >> 2, hq = f & 3;
        float4 v0 = *(const float4*)(vb + (size_t)(2 * p)     * 512 + hq * 4);
        float4 v1 = *(const float4*)(vb + (size_t)(2 * p + 1) * 512 + hq * 4);
        vsT[hq * 4 + 0][p] = pk_bf16(v0.x, v1.x);
        vsT[hq * 4 + 1][p] = pk_bf16(v0.y, v1.y);
        vsT[hq * 4 + 2][p] = pk_bf16(v0.z, v1.z);
        vsT[hq * 4 + 3][p] = pk_bf16(v0.w, v1.w);
    }
    __syncthreads();

    const int wave = t >> 6, lane = t & 63;
    const int ml = lane & 15;             // m-offset (QK^T D col) / h (PV D col)
    const int g  = lane >> 4;             // k-group
    const int m0w = m0b + wave * 16;

    // ---- Q fragment (B operand), 0.25 scale folded; k 16..31 zero ----
    FragU qf;
    if (g < 2) {
        const float* qr = q + (size_t)b * 524288
                            + (size_t)(m0w + ml) * 512 + c * 16 + g * 8;
        float4 a  = *(const float4*)qr;
        float4 bq = *(const float4*)(qr + 4);
        qf.u[0] = pk_bf16(a.x * 0.25f, a.y * 0.25f);
        qf.u[1] = pk_bf16(a.z * 0.25f, a.w * 0.25f);
        qf.u[2] = pk_bf16(bq.x * 0.25f, bq.y * 0.25f);
        qf.u[3] = pk_bf16(bq.z * 0.25f, bq.w * 0.25f);
    } else {
        qf.u = (u32x4){0, 0, 0, 0};
    }

    const f32x4 zero4 = {0.f, 0.f, 0.f, 0.f};

    // ---- pass 1: row sums ----
    float rs = 0.f;
#pragma unroll 1
    for (int nt = 0; nt < 64; ++nt) {
        FragU ka;
        if (lane < 32) ka.u = *(const u32x4*)&ksF[nt * 128 + lane * 4];
        else           ka.u = (u32x4){0, 0, 0, 0};
        f32x4 st = __builtin_amdgcn_mfma_f32_16x16x32_bf16(ka.s, qf.s, zero4, 0, 0, 0);
        rs += (__expf(st[0]) + __expf(st[1])) + (__expf(st[2]) + __expf(st[3]));
    }
    rs += __shfl_xor(rs, 16);
    rs += __shfl_xor(rs, 32);
    const float inv = 1.0f / rs;

    // ---- pass 2: weights store + PV ----
    f32x4 acc = zero4;
    float* wrow = wts + (size_t)cb * 1048576 + (size_t)(m0w + ml) * 1024;
#pragma unroll 1
    for (int ntp = 0; ntp < 32; ++ntp) {
#pragma unroll
        for (int sub = 0; sub < 2; ++sub) {
            const int nt = ntp * 2 + sub;
            FragU ka;
            if (lane < 32) ka.u = *(const u32x4*)&ksF[nt * 128 + lane * 4];
            else           ka.u = (u32x4){0, 0, 0, 0};
            f32x4 st = __builtin_amdgcn_mfma_f32_16x16x32_bf16(ka.s, qf.s, zero4, 0, 0, 0);
            float w0 = __expf(st[0]) * inv;
            float w1 = __expf(st[1]) * inv;
            float w2 = __expf(st[2]) * inv;
            float w3 = __expf(st[3]) * inv;
            // weights: reg r -> n = nt*16 + g*4 + r, row m = m0w+ml
            *(float4*)(wrow + nt * 16 + g * 4) = make_float4(w0, w1, w2, w3);
            // P tile to per-wave LDS: [m=ml][n-pair = sub*8 + g*2 + {0,1}]
            unsigned* pb = &pbuf[wave][ml][sub * 8 + g * 2];
            pb[0] = pk_bf16(w0, w1);
            pb[1] = pk_bf16(w2, w3);
        }
        // PV over this 32-n block (same-wave LDS: in-order, compiler waits)
        FragU pa, vf;
        pa.u = *(const u32x4*)&pbuf[wave][ml][g * 4];           // row m=ml, k pairs
        vf.u = *(const u32x4*)&vsT[ml][ntp * 16 + g * 4];       // col h=ml, k pairs
        acc = __builtin_amdgcn_mfma_f32_16x16x32_bf16(pa.s, vf.s, acc, 0, 0, 0);
    }

    // ---- att write (scrambled): D2 row = m-offset g*4+r, col = h = ml ----
    const int b2 = c >> 4;
#pragma unroll
    for (int r = 0; r < 4; ++r) {
        const int m  = m0w + g * 4 + r;
        const int m2 = (c & 15) * 64 + (m >> 4);
        const int d2 = (m & 15) * 32 + b * 16 + ml;
        att[((size_t)b2 * 1024 + m2) * 512 + d2] = acc[r];
    }
}

// ---------------------------------------------------------------------------
extern "C" void kernel_launch(void* const* d_in, const int* in_sizes, int n_in,
                              void* d_out, int out_size, void* d_ws, size_t ws_size,
                              hipStream_t stream)
{
    (void)in_sizes; (void)n_in; (void)out_size; (void)ws_size;
    const float* Q  = (const float*)d_in[0];
    const float* K  = (const float*)d_in[1];
    const float* V  = (const float*)d_in[2];
    const float* Wq = (const float*)d_in[3];
    const float* Wk = (const float*)d_in[4];
    const float* Wv = (const float*)d_in[5];
    const float* Wo = (const float*)d_in[6];

    float* out = (float*)d_out;
    float* wts = out + 1048576;            // weights output region (64M floats)

    float* ws  = (float*)d_ws;
    float* q   = ws;                        // 1M floats
    float* k   = ws + (1u << 20);           // 1M
    float* v   = ws + 2 * (1u << 20);       // 1M
    float* att = ws + 3 * (1u << 20);       // 1M (scrambled out_pre)

    proj3_kernel<<<dim3(8, 32, 3), 256, 0, stream>>>(Q, K, V, Wq, Wk, Wv, q, k, v);
    attn_mfma_kernel<<<512, 512, 0, stream>>>(q, k, v, wts, att);
    outproj_kernel<<<dim3(8, 32, 1), 256, 0, stream>>>(att, Wo, out);
}